// Round 2
// baseline (12813.878 us; speedup 1.0000x reference)
//
#include <hip/hip_runtime.h>
#include <hip/hip_bf16.h>

#define N_USERS 100000
#define N_ITEMS 50000
#define N_NODES 150000
#define DD 64
#define FF 768
#define N_EDGES_C 4800000
#define BATCH 4096
#define LN_EPS 1e-5f
#define CONTENT_LOSS_W 0.1f

// ---------------------------------------------------------------------------
// K1: emb/acc init for user nodes, zero loss slot
// ---------------------------------------------------------------------------
__global__ __launch_bounds__(256) void init_users_k(
    const float* __restrict__ ue,
    float* __restrict__ emb, float* __restrict__ acc,
    float* __restrict__ loss_slot)
{
    int gid = blockIdx.x * 256 + threadIdx.x;
    if (gid == 0) loss_slot[0] = 0.f;
    size_t base = (size_t)gid * 4;  // N_USERS*DD / 4 = 1.6M threads, exact
    float4 v = *reinterpret_cast<const float4*>(ue + base);
    *reinterpret_cast<float4*>(emb + base) = v;
    *reinterpret_cast<float4*>(acc + base) = v;
}

// ---------------------------------------------------------------------------
// K2: items_content = cf @ W + b ; gate = sigmoid(cf @ wg + bg)
//     items = (1-gate)*item_emb + gate*items_content
//     16 rows per block, cf tile staged in LDS (48 KB).
// ---------------------------------------------------------------------------
__global__ __launch_bounds__(256) void content_combine_k(
    const float* __restrict__ cf,   // (N_ITEMS, FF)
    const float* __restrict__ Wp,   // (FF, DD)
    const float* __restrict__ bp,   // (DD)
    const float* __restrict__ wg,   // (FF)
    const float* __restrict__ bg,   // (1)
    const float* __restrict__ item_emb, // (N_ITEMS, DD)
    float* __restrict__ items_content,  // ws (N_ITEMS, DD)
    float* __restrict__ emb, float* __restrict__ acc)
{
    __shared__ float cf_s[16][FF];           // 48 KB
    const int tid = threadIdx.x;
    const int row0 = blockIdx.x * 16;

    // ---- stage 16 rows of cf (f32, float4 loads) ----
    {
        const int lrow = tid >> 4;           // 0..15
        const int sub  = tid & 15;           // 0..15
        const float* src = cf + (size_t)(row0 + lrow) * FF;
        #pragma unroll
        for (int i = 0; i < 12; ++i) {
            int k = sub * 4 + i * 64;
            float4 u = *reinterpret_cast<const float4*>(src + k);
            *reinterpret_cast<float4*>(&cf_s[lrow][k]) = u;
        }
    }
    __syncthreads();

    const int lane = tid & 63;
    const int rg   = tid >> 6;               // wave id 0..3 -> rows rg*4..rg*4+3
    const int rbase = rg * 4;

    // ---- gate for this wave's 4 rows ----
    float g[4];
    const float bgv = bg[0];
    #pragma unroll
    for (int r = 0; r < 4; ++r) {
        float gp = 0.f;
        for (int k = lane; k < FF; k += 64)
            gp += cf_s[rbase + r][k] * wg[k];
        #pragma unroll
        for (int off = 32; off; off >>= 1) gp += __shfl_xor(gp, off);
        g[r] = 1.f / (1.f + __expf(-(gp + bgv)));
    }

    // ---- projection: lane = output col, 4 rows interleaved ----
    float a0 = 0.f, a1 = 0.f, a2 = 0.f, a3 = 0.f;
    #pragma unroll 4
    for (int k = 0; k < FF; ++k) {
        float wv = Wp[k * DD + lane];
        a0 += cf_s[rbase + 0][k] * wv;
        a1 += cf_s[rbase + 1][k] * wv;
        a2 += cf_s[rbase + 2][k] * wv;
        a3 += cf_s[rbase + 3][k] * wv;
    }

    const float bpv = bp[lane];
    float av[4] = {a0, a1, a2, a3};
    #pragma unroll
    for (int r = 0; r < 4; ++r) {
        int row = row0 + rbase + r;
        float ic = av[r] + bpv;
        float gr = g[r];
        float it = (1.f - gr) * item_emb[(size_t)row * DD + lane] + gr * ic;
        items_content[(size_t)row * DD + lane] = ic;
        size_t o = (size_t)(N_USERS + row) * DD + lane;
        emb[o] = it;
        acc[o] = it;
    }
}

// ---------------------------------------------------------------------------
// K3: edge scatter: agg[dst] += w * emb[src]   (atomic f32)
//     16 threads per edge, 4 cols each
// ---------------------------------------------------------------------------
__global__ __launch_bounds__(256) void scatter_k(
    const int* __restrict__ es, const int* __restrict__ ed,
    const float* __restrict__ ew,
    const float* __restrict__ emb, float* __restrict__ agg)
{
    int gid = blockIdx.x * 256 + threadIdx.x;   // N_EDGES*16 threads
    int e  = gid >> 4;
    int c4 = (gid & 15) * 4;
    int s = es[e];
    int d = ed[e];
    float w = ew[e];
    float4 v = *reinterpret_cast<const float4*>(emb + (size_t)s * DD + c4);
    float* dst = agg + (size_t)d * DD + c4;
    atomicAdd(dst + 0, w * v.x);
    atomicAdd(dst + 1, w * v.y);
    atomicAdd(dst + 2, w * v.z);
    atomicAdd(dst + 3, w * v.w);
}

// ---------------------------------------------------------------------------
// K4: emb = layernorm(agg) + emb ; acc += emb   (wave per node)
// ---------------------------------------------------------------------------
__global__ __launch_bounds__(256) void ln_residual_k(
    const float* __restrict__ agg, float* __restrict__ emb,
    float* __restrict__ acc)
{
    int n = blockIdx.x * 4 + (threadIdx.x >> 6);
    int c = threadIdx.x & 63;
    size_t o = (size_t)n * DD + c;
    float a = agg[o];
    float s = a;
    #pragma unroll
    for (int off = 32; off; off >>= 1) s += __shfl_xor(s, off);
    float m = s * (1.f / 64.f);
    float dlt = a - m;
    float vv = dlt * dlt;
    #pragma unroll
    for (int off = 32; off; off >>= 1) vv += __shfl_xor(vv, off);
    float var = vv * (1.f / 64.f);
    float y = dlt * rsqrtf(var + LN_EPS);
    float e = y + emb[o];
    emb[o] = e;
    acc[o] += e;
}

// ---------------------------------------------------------------------------
// K5: gather outputs (users / pos / neg), scale by 1/4, f32 out
// ---------------------------------------------------------------------------
__global__ __launch_bounds__(256) void gather_out_k(
    const int* __restrict__ users, const int* __restrict__ pos,
    const int* __restrict__ neg, const float* __restrict__ acc,
    float* __restrict__ out)
{
    int gid = blockIdx.x * 256 + threadIdx.x;   // 3*BATCH*DD
    int part = gid / (BATCH * DD);
    int r = gid - part * (BATCH * DD);
    int b = r >> 6, c = r & 63;
    int node;
    if (part == 0)      node = users[b];
    else if (part == 1) node = N_USERS + pos[b];
    else                node = N_USERS + neg[b];
    out[gid] = acc[(size_t)node * DD + c] * 0.25f;
}

// ---------------------------------------------------------------------------
// K6: content loss partial sums -> atomicAdd into loss slot
// ---------------------------------------------------------------------------
__global__ __launch_bounds__(256) void loss_k(
    const float* __restrict__ acc, const float* __restrict__ ic,
    float* __restrict__ loss_slot)
{
    const int total = N_ITEMS * DD;
    int stride = gridDim.x * 256;
    float p = 0.f;
    for (int i = blockIdx.x * 256 + threadIdx.x; i < total; i += stride) {
        float fi = acc[(size_t)N_USERS * DD + i] * 0.25f;
        float d = fi - ic[i];
        p += d * d;
    }
    #pragma unroll
    for (int off = 32; off; off >>= 1) p += __shfl_xor(p, off);
    __shared__ float red[4];
    if ((threadIdx.x & 63) == 0) red[threadIdx.x >> 6] = p;
    __syncthreads();
    if (threadIdx.x == 0)
        atomicAdd(loss_slot, red[0] + red[1] + red[2] + red[3]);
}

__global__ void finalize_loss_k(const float* __restrict__ loss_slot,
                                float* __restrict__ out)
{
    out[3 * BATCH * DD] =
        loss_slot[0] * (CONTENT_LOSS_W / (float)(N_ITEMS * DD));
}

// ---------------------------------------------------------------------------
extern "C" void kernel_launch(void* const* d_in, const int* in_sizes, int n_in,
                              void* d_out, int out_size, void* d_ws, size_t ws_size,
                              hipStream_t stream)
{
    const int* users = (const int*)d_in[0];
    const int* pos   = (const int*)d_in[1];
    const int* neg   = (const int*)d_in[2];
    const int* es    = (const int*)d_in[3];
    const int* ed    = (const int*)d_in[4];
    const float* ew  = (const float*)d_in[5];
    const float* ue  = (const float*)d_in[6];
    const float* ie  = (const float*)d_in[7];
    const float* cf  = (const float*)d_in[8];
    const float* Wp  = (const float*)d_in[9];
    const float* bp  = (const float*)d_in[10];
    const float* wg  = (const float*)d_in[11];
    const float* bg  = (const float*)d_in[12];
    float* out = (float*)d_out;

    // workspace layout (f32): emb | acc | agg | items_content | loss
    float* emb = (float*)d_ws;
    float* acc = emb + (size_t)N_NODES * DD;
    float* agg = acc + (size_t)N_NODES * DD;
    float* ic  = agg + (size_t)N_NODES * DD;
    float* loss_slot = ic + (size_t)N_ITEMS * DD;

    init_users_k<<<(N_USERS * DD / 4) / 256, 256, 0, stream>>>(ue, emb, acc, loss_slot);
    content_combine_k<<<N_ITEMS / 16, 256, 0, stream>>>(cf, Wp, bp, wg, bg, ie, ic, emb, acc);

    for (int l = 0; l < 3; ++l) {
        hipMemsetAsync(agg, 0, (size_t)N_NODES * DD * sizeof(float), stream);
        scatter_k<<<(N_EDGES_C * 16) / 256, 256, 0, stream>>>(es, ed, ew, emb, agg);
        ln_residual_k<<<N_NODES / 4, 256, 0, stream>>>(agg, emb, acc);
    }

    gather_out_k<<<(3 * BATCH * DD) / 256, 256, 0, stream>>>(users, pos, neg, acc, out);
    loss_k<<<2048, 256, 0, stream>>>(acc, ic, loss_slot);
    finalize_loss_k<<<1, 1, 0, stream>>>(loss_slot, out);
}

// Round 3
// 2467.328 us; speedup vs baseline: 5.1934x; 5.1934x over previous
//
#include <hip/hip_runtime.h>
#include <hip/hip_bf16.h>

#define N_USERS 100000
#define N_ITEMS 50000
#define N_NODES 150000
#define DD 64
#define FF 768
#define N_EDGES_C 4800000
#define BATCH 4096
#define LN_EPS 1e-5f
#define CONTENT_LOSS_W 0.1f

#define SCAN_BLK 1024
#define SCAN_NBLK 147   // ceil(150000/1024)

// ---------------------------------------------------------------------------
// K1: emb init for user nodes
// ---------------------------------------------------------------------------
__global__ __launch_bounds__(256) void init_users_k(
    const float* __restrict__ ue, float* __restrict__ emb)
{
    int gid = blockIdx.x * 256 + threadIdx.x;
    size_t base = (size_t)gid * 4;  // N_USERS*DD/4 = 1.6M threads, exact
    float4 v = *reinterpret_cast<const float4*>(ue + base);
    *reinterpret_cast<float4*>(emb + base) = v;
}

// ---------------------------------------------------------------------------
// K2: items_content = cf @ W + b ; gate = sigmoid(cf @ wg + bg)
//     items = (1-gate)*item_emb + gate*items_content
//     writes emb item rows + acc_items init
// ---------------------------------------------------------------------------
__global__ __launch_bounds__(256) void content_combine_k(
    const float* __restrict__ cf,   // (N_ITEMS, FF)
    const float* __restrict__ Wp,   // (FF, DD)
    const float* __restrict__ bp,   // (DD)
    const float* __restrict__ wg,   // (FF)
    const float* __restrict__ bg,   // (1)
    const float* __restrict__ item_emb, // (N_ITEMS, DD)
    float* __restrict__ items_content,  // (N_ITEMS, DD)
    float* __restrict__ emb, float* __restrict__ acc_items)
{
    __shared__ float cf_s[16][FF];           // 48 KB
    const int tid = threadIdx.x;
    const int row0 = blockIdx.x * 16;

    {
        const int lrow = tid >> 4;
        const int sub  = tid & 15;
        const float* src = cf + (size_t)(row0 + lrow) * FF;
        #pragma unroll
        for (int i = 0; i < 12; ++i) {
            int k = sub * 4 + i * 64;
            float4 u = *reinterpret_cast<const float4*>(src + k);
            *reinterpret_cast<float4*>(&cf_s[lrow][k]) = u;
        }
    }
    __syncthreads();

    const int lane = tid & 63;
    const int rg   = tid >> 6;
    const int rbase = rg * 4;

    float g[4];
    const float bgv = bg[0];
    #pragma unroll
    for (int r = 0; r < 4; ++r) {
        float gp = 0.f;
        for (int k = lane; k < FF; k += 64)
            gp += cf_s[rbase + r][k] * wg[k];
        #pragma unroll
        for (int off = 32; off; off >>= 1) gp += __shfl_xor(gp, off);
        g[r] = 1.f / (1.f + __expf(-(gp + bgv)));
    }

    float a0 = 0.f, a1 = 0.f, a2 = 0.f, a3 = 0.f;
    #pragma unroll 4
    for (int k = 0; k < FF; ++k) {
        float wv = Wp[k * DD + lane];
        a0 += cf_s[rbase + 0][k] * wv;
        a1 += cf_s[rbase + 1][k] * wv;
        a2 += cf_s[rbase + 2][k] * wv;
        a3 += cf_s[rbase + 3][k] * wv;
    }

    const float bpv = bp[lane];
    float av[4] = {a0, a1, a2, a3};
    #pragma unroll
    for (int r = 0; r < 4; ++r) {
        int row = row0 + rbase + r;
        float ic = av[r] + bpv;
        float gr = g[r];
        float it = (1.f - gr) * item_emb[(size_t)row * DD + lane] + gr * ic;
        items_content[(size_t)row * DD + lane] = ic;
        emb[(size_t)(N_USERS + row) * DD + lane] = it;
        acc_items[(size_t)row * DD + lane] = it;
    }
}

// ---------------------------------------------------------------------------
// CSR build: histogram -> scan -> fill
// ---------------------------------------------------------------------------
__global__ __launch_bounds__(256) void hist_k(
    const int* __restrict__ ed, int* __restrict__ deg)
{
    int e = blockIdx.x * 256 + threadIdx.x;
    if (e < N_EDGES_C) atomicAdd(&deg[ed[e]], 1);
}

__global__ __launch_bounds__(SCAN_BLK) void scan_blocksum_k(
    const int* __restrict__ deg, int* __restrict__ partials)
{
    __shared__ int sdata[SCAN_BLK];
    int i = blockIdx.x * SCAN_BLK + threadIdx.x;
    int v = (i < N_NODES) ? deg[i] : 0;
    sdata[threadIdx.x] = v;
    __syncthreads();
    // tree reduce
    for (int off = SCAN_BLK / 2; off; off >>= 1) {
        if (threadIdx.x < off) sdata[threadIdx.x] += sdata[threadIdx.x + off];
        __syncthreads();
    }
    if (threadIdx.x == 0) partials[blockIdx.x] = sdata[0];
}

__global__ __launch_bounds__(256) void scan_partials_k(int* __restrict__ partials)
{
    __shared__ int sdata[256];
    int t = threadIdx.x;
    int v = (t < SCAN_NBLK) ? partials[t] : 0;
    sdata[t] = v;
    __syncthreads();
    for (int off = 1; off < 256; off <<= 1) {
        int x = (t >= off) ? sdata[t - off] : 0;
        __syncthreads();
        sdata[t] += x;
        __syncthreads();
    }
    // exclusive
    if (t < SCAN_NBLK) partials[t] = sdata[t] - v;
}

__global__ __launch_bounds__(SCAN_BLK) void scan_write_k(
    const int* __restrict__ deg, const int* __restrict__ partials,
    int* __restrict__ row_ptr, int* __restrict__ cursor)
{
    __shared__ int sdata[SCAN_BLK];
    int i = blockIdx.x * SCAN_BLK + threadIdx.x;
    int t = threadIdx.x;
    int v = (i < N_NODES) ? deg[i] : 0;
    sdata[t] = v;
    __syncthreads();
    for (int off = 1; off < SCAN_BLK; off <<= 1) {
        int x = (t >= off) ? sdata[t - off] : 0;
        __syncthreads();
        sdata[t] += x;
        __syncthreads();
    }
    if (i < N_NODES) {
        int row = partials[blockIdx.x] + sdata[t] - v;  // exclusive
        row_ptr[i] = row;
        cursor[i]  = row;
    }
    if (i == 0) row_ptr[N_NODES] = N_EDGES_C;
}

__global__ __launch_bounds__(256) void fill_k(
    const int* __restrict__ ed, int* __restrict__ cursor,
    int* __restrict__ eidx)
{
    int e = blockIdx.x * 256 + threadIdx.x;
    if (e < N_EDGES_C) {
        int p = atomicAdd(&cursor[ed[e]], 1);
        eidx[p] = e;
    }
}

// ---------------------------------------------------------------------------
// K3: fused aggregate + layernorm + residual.  wave per node, lane = col.
//     emb_out[n] = LN(sum_{e in CSR[n]} w_e * emb_in[src_e]) + emb_in[n]
//     acc_items[n] += emb_out[n] for item rows
// ---------------------------------------------------------------------------
__global__ __launch_bounds__(256) void agg_ln_k(
    const float* __restrict__ emb_in, float* __restrict__ emb_out,
    float* __restrict__ acc_items,
    const int* __restrict__ row_ptr, const int* __restrict__ eidx,
    const int* __restrict__ es, const float* __restrict__ ew)
{
    int n = blockIdx.x * 4 + (threadIdx.x >> 6);   // 37500 blocks exact
    int lane = threadIdx.x & 63;
    int beg = row_ptr[n], end = row_ptr[n + 1];

    float a = 0.f;
    int j = beg;
    for (; j + 1 < end; j += 2) {
        int e0 = eidx[j], e1 = eidx[j + 1];
        float w0 = ew[e0], w1 = ew[e1];
        int s0 = es[e0], s1 = es[e1];
        float v0 = emb_in[(size_t)s0 * DD + lane];
        float v1 = emb_in[(size_t)s1 * DD + lane];
        a += w0 * v0;
        a += w1 * v1;
    }
    if (j < end) {
        int e0 = eidx[j];
        a += ew[e0] * emb_in[(size_t)es[e0] * DD + lane];
    }

    float s = a;
    #pragma unroll
    for (int off = 32; off; off >>= 1) s += __shfl_xor(s, off);
    float m = s * (1.f / 64.f);
    float dlt = a - m;
    float vv = dlt * dlt;
    #pragma unroll
    for (int off = 32; off; off >>= 1) vv += __shfl_xor(vv, off);
    float var = vv * (1.f / 64.f);
    float y = dlt * rsqrtf(var + LN_EPS);

    size_t o = (size_t)n * DD + lane;
    float e_new = y + emb_in[o];
    emb_out[o] = e_new;
    if (n >= N_USERS)
        acc_items[(size_t)(n - N_USERS) * DD + lane] += e_new;
}

// ---------------------------------------------------------------------------
// K4: accumulate emb state at sampled output slots
// ---------------------------------------------------------------------------
__global__ __launch_bounds__(256) void gather_acc_k(
    const int* __restrict__ users, const int* __restrict__ pos,
    const int* __restrict__ neg, const float* __restrict__ emb_state,
    float* __restrict__ out_acc, int init)
{
    int gid = blockIdx.x * 256 + threadIdx.x;   // 3*BATCH*DD = 786432
    int part = gid / (BATCH * DD);
    int r = gid - part * (BATCH * DD);
    int b = r >> 6, c = r & 63;
    int node;
    if (part == 0)      node = users[b];
    else if (part == 1) node = N_USERS + pos[b];
    else                node = N_USERS + neg[b];
    float v = emb_state[(size_t)node * DD + c];
    if (init) out_acc[gid] = v;
    else      out_acc[gid] += v;
}

// ---------------------------------------------------------------------------
// K5: content loss
// ---------------------------------------------------------------------------
__global__ __launch_bounds__(256) void loss_k(
    const float* __restrict__ acc_items, const float* __restrict__ ic,
    float* __restrict__ loss_slot)
{
    const int total = N_ITEMS * DD;
    int stride = gridDim.x * 256;
    float p = 0.f;
    for (int i = blockIdx.x * 256 + threadIdx.x; i < total; i += stride) {
        float d = acc_items[i] * 0.25f - ic[i];
        p += d * d;
    }
    #pragma unroll
    for (int off = 32; off; off >>= 1) p += __shfl_xor(p, off);
    __shared__ float red[4];
    if ((threadIdx.x & 63) == 0) red[threadIdx.x >> 6] = p;
    __syncthreads();
    if (threadIdx.x == 0)
        atomicAdd(loss_slot, red[0] + red[1] + red[2] + red[3]);
}

// ---------------------------------------------------------------------------
// K6: final output: out = out_acc * 0.25, plus loss element
// ---------------------------------------------------------------------------
__global__ __launch_bounds__(256) void final_out_k(
    const float* __restrict__ out_acc, const float* __restrict__ loss_slot,
    float* __restrict__ out)
{
    int gid = blockIdx.x * 256 + threadIdx.x;
    out[gid] = out_acc[gid] * 0.25f;
    if (gid == 0)
        out[3 * BATCH * DD] =
            loss_slot[0] * (CONTENT_LOSS_W / (float)(N_ITEMS * DD));
}

// ---------------------------------------------------------------------------
extern "C" void kernel_launch(void* const* d_in, const int* in_sizes, int n_in,
                              void* d_out, int out_size, void* d_ws, size_t ws_size,
                              hipStream_t stream)
{
    const int* users = (const int*)d_in[0];
    const int* pos   = (const int*)d_in[1];
    const int* neg   = (const int*)d_in[2];
    const int* es    = (const int*)d_in[3];
    const int* ed    = (const int*)d_in[4];
    const float* ew  = (const float*)d_in[5];
    const float* ue  = (const float*)d_in[6];
    const float* ie  = (const float*)d_in[7];
    const float* cf  = (const float*)d_in[8];
    const float* Wp  = (const float*)d_in[9];
    const float* bp  = (const float*)d_in[10];
    const float* wg  = (const float*)d_in[11];
    const float* bg  = (const float*)d_in[12];
    float* out = (float*)d_out;

    // ---- workspace layout (~126.5 MB) ----
    float* embA      = (float*)d_ws;                       // 9.6M f
    float* embB      = embA + (size_t)N_NODES * DD;        // 9.6M f
    float* acc_items = embB + (size_t)N_NODES * DD;        // 3.2M f
    float* ic        = acc_items + (size_t)N_ITEMS * DD;   // 3.2M f
    float* out_acc   = ic + (size_t)N_ITEMS * DD;          // 786432 f
    float* loss_slot = out_acc + 3 * BATCH * DD;           // 16 f pad
    int*   deg       = (int*)(loss_slot + 16);             // 150016
    int*   row_ptr   = deg + 150016;                       // 150016
    int*   cursor    = row_ptr + 150016;                   // 150016
    int*   partials  = cursor + 150016;                    // 256
    int*   eidx      = partials + 256;                     // 4.8M

    hipMemsetAsync(deg, 0, 150016 * sizeof(int), stream);
    hipMemsetAsync(loss_slot, 0, sizeof(float), stream);

    init_users_k<<<(N_USERS * DD / 4) / 256, 256, 0, stream>>>(ue, embA);
    content_combine_k<<<N_ITEMS / 16, 256, 0, stream>>>(cf, Wp, bp, wg, bg, ie,
                                                        ic, embA, acc_items);
    // layer-0 state into out_acc
    gather_acc_k<<<3 * BATCH * DD / 256, 256, 0, stream>>>(users, pos, neg,
                                                           embA, out_acc, 1);
    // CSR build
    hist_k<<<(N_EDGES_C + 255) / 256, 256, 0, stream>>>(ed, deg);
    scan_blocksum_k<<<SCAN_NBLK, SCAN_BLK, 0, stream>>>(deg, partials);
    scan_partials_k<<<1, 256, 0, stream>>>(partials);
    scan_write_k<<<SCAN_NBLK, SCAN_BLK, 0, stream>>>(deg, partials, row_ptr, cursor);
    fill_k<<<(N_EDGES_C + 255) / 256, 256, 0, stream>>>(ed, cursor, eidx);

    // 3 propagation layers, ping-pong embA/embB
    float* cur = embA;
    float* nxt = embB;
    for (int l = 0; l < 3; ++l) {
        agg_ln_k<<<N_NODES / 4, 256, 0, stream>>>(cur, nxt, acc_items,
                                                  row_ptr, eidx, es, ew);
        gather_acc_k<<<3 * BATCH * DD / 256, 256, 0, stream>>>(users, pos, neg,
                                                               nxt, out_acc, 0);
        float* t = cur; cur = nxt; nxt = t;
    }

    loss_k<<<2048, 256, 0, stream>>>(acc_items, ic, loss_slot);
    final_out_k<<<3 * BATCH * DD / 256, 256, 0, stream>>>(out_acc, loss_slot, out);
}

// Round 5
// 1719.157 us; speedup vs baseline: 7.4536x; 1.4352x over previous
//
#include <hip/hip_runtime.h>
#include <hip/hip_bf16.h>

#define N_USERS 100000
#define N_ITEMS 50000
#define N_NODES 150000
#define DD 64
#define FF 768
#define N_EDGES_C 4800000
#define BATCH 4096
#define LN_EPS 1e-5f
#define CONTENT_LOSS_W 0.1f

#define SCAN_BLK 1024
#define SCAN_NBLK 147   // ceil(150000/1024)

__device__ inline float b2f(unsigned short v) {
    union { unsigned int i; float f; } u;
    u.i = ((unsigned int)v) << 16;
    return u.f;
}
__device__ inline unsigned short f2b(float f) {
    union { float f; unsigned int i; } u; u.f = f;
    unsigned int r = u.i + 0x7fff + ((u.i >> 16) & 1);   // RNE
    return (unsigned short)(r >> 16);
}

// ---------------------------------------------------------------------------
// K1: user emb init f32 -> bf16
// ---------------------------------------------------------------------------
__global__ __launch_bounds__(256) void init_users_k(
    const float* __restrict__ ue, unsigned short* __restrict__ emb)
{
    int gid = blockIdx.x * 256 + threadIdx.x;   // N_USERS*DD/4 threads
    size_t base = (size_t)gid * 4;
    float4 v = *reinterpret_cast<const float4*>(ue + base);
    ushort4 o;
    o.x = f2b(v.x); o.y = f2b(v.y); o.z = f2b(v.z); o.w = f2b(v.w);
    *reinterpret_cast<ushort4*>(emb + base) = o;
}

// ---------------------------------------------------------------------------
// K2: content projection + gate + combine
// ---------------------------------------------------------------------------
__global__ __launch_bounds__(256) void content_combine_k(
    const float* __restrict__ cf, const float* __restrict__ Wp,
    const float* __restrict__ bp, const float* __restrict__ wg,
    const float* __restrict__ bg, const float* __restrict__ item_emb,
    float* __restrict__ items_content,
    unsigned short* __restrict__ emb, float* __restrict__ acc_items)
{
    __shared__ float cf_s[16][FF];           // 48 KB
    const int tid = threadIdx.x;
    const int row0 = blockIdx.x * 16;

    {
        const int lrow = tid >> 4;
        const int sub  = tid & 15;
        const float* src = cf + (size_t)(row0 + lrow) * FF;
        #pragma unroll
        for (int i = 0; i < 12; ++i) {
            int k = sub * 4 + i * 64;
            float4 u = *reinterpret_cast<const float4*>(src + k);
            *reinterpret_cast<float4*>(&cf_s[lrow][k]) = u;
        }
    }
    __syncthreads();

    const int lane = tid & 63;
    const int rg   = tid >> 6;
    const int rbase = rg * 4;

    float g[4];
    const float bgv = bg[0];
    #pragma unroll
    for (int r = 0; r < 4; ++r) {
        float gp = 0.f;
        for (int k = lane; k < FF; k += 64)
            gp += cf_s[rbase + r][k] * wg[k];
        #pragma unroll
        for (int off = 32; off; off >>= 1) gp += __shfl_xor(gp, off);
        g[r] = 1.f / (1.f + __expf(-(gp + bgv)));
    }

    float a0 = 0.f, a1 = 0.f, a2 = 0.f, a3 = 0.f;
    #pragma unroll 4
    for (int k = 0; k < FF; ++k) {
        float wv = Wp[k * DD + lane];
        a0 += cf_s[rbase + 0][k] * wv;
        a1 += cf_s[rbase + 1][k] * wv;
        a2 += cf_s[rbase + 2][k] * wv;
        a3 += cf_s[rbase + 3][k] * wv;
    }

    const float bpv = bp[lane];
    float av[4] = {a0, a1, a2, a3};
    #pragma unroll
    for (int r = 0; r < 4; ++r) {
        int row = row0 + rbase + r;
        float ic = av[r] + bpv;
        float gr = g[r];
        float it = (1.f - gr) * item_emb[(size_t)row * DD + lane] + gr * ic;
        items_content[(size_t)row * DD + lane] = ic;
        emb[(size_t)(N_USERS + row) * DD + lane] = f2b(it);
        acc_items[(size_t)row * DD + lane] = it;
    }
}

// ---------------------------------------------------------------------------
// CSR build: cursor doubles as histogram -> start offsets -> end offsets
// ---------------------------------------------------------------------------
__global__ __launch_bounds__(256) void hist_k(
    const int* __restrict__ ed, int* __restrict__ cursor)
{
    int t = blockIdx.x * 256 + threadIdx.x;  // ceil(N_EDGES/4 / 256) blocks
    if (t < N_EDGES_C / 4) {
        int4 d = reinterpret_cast<const int4*>(ed)[t];
        atomicAdd(&cursor[d.x], 1);
        atomicAdd(&cursor[d.y], 1);
        atomicAdd(&cursor[d.z], 1);
        atomicAdd(&cursor[d.w], 1);
    }
}

__global__ __launch_bounds__(SCAN_BLK) void scan_blocksum_k(
    const int* __restrict__ cursor, int* __restrict__ partials)
{
    __shared__ int sdata[SCAN_BLK];
    int i = blockIdx.x * SCAN_BLK + threadIdx.x;
    int v = (i < N_NODES) ? cursor[i] : 0;
    sdata[threadIdx.x] = v;
    __syncthreads();
    for (int off = SCAN_BLK / 2; off; off >>= 1) {
        if (threadIdx.x < off) sdata[threadIdx.x] += sdata[threadIdx.x + off];
        __syncthreads();
    }
    if (threadIdx.x == 0) partials[blockIdx.x] = sdata[0];
}

__global__ __launch_bounds__(256) void scan_partials_k(int* __restrict__ partials)
{
    __shared__ int sdata[256];
    int t = threadIdx.x;
    int v = (t < SCAN_NBLK) ? partials[t] : 0;
    sdata[t] = v;
    __syncthreads();
    for (int off = 1; off < 256; off <<= 1) {
        int x = (t >= off) ? sdata[t - off] : 0;
        __syncthreads();
        sdata[t] += x;
        __syncthreads();
    }
    if (t < SCAN_NBLK) partials[t] = sdata[t] - v;   // exclusive
}

__global__ __launch_bounds__(SCAN_BLK) void scan_write_k(
    const int* __restrict__ partials, int* __restrict__ cursor)
{
    __shared__ int sdata[SCAN_BLK];
    int i = blockIdx.x * SCAN_BLK + threadIdx.x;
    int t = threadIdx.x;
    int v = (i < N_NODES) ? cursor[i] : 0;
    sdata[t] = v;
    __syncthreads();
    for (int off = 1; off < SCAN_BLK; off <<= 1) {
        int x = (t >= off) ? sdata[t - off] : 0;
        __syncthreads();
        sdata[t] += x;
        __syncthreads();
    }
    if (i < N_NODES)
        cursor[i] = partials[blockIdx.x] + sdata[t] - v;   // exclusive start
}

// fill: adj[p] = {src, w_bits}; cursor becomes end offsets
__global__ __launch_bounds__(256) void fill_k(
    const int* __restrict__ ed, const int* __restrict__ es,
    const float* __restrict__ ew, int* __restrict__ cursor,
    uint2* __restrict__ adj)
{
    int e = blockIdx.x * 256 + threadIdx.x;
    int d = ed[e];
    int s = es[e];
    float w = ew[e];
    int p = atomicAdd(&cursor[d], 1);
    adj[p] = make_uint2((unsigned)s, __float_as_uint(w));
}

// ---------------------------------------------------------------------------
// K3: fused aggregate + layernorm + residual (bf16 emb state)
// ---------------------------------------------------------------------------
__global__ __launch_bounds__(256) void agg_ln_k(
    const unsigned short* __restrict__ emb_in,
    unsigned short* __restrict__ emb_out,
    float* __restrict__ acc_items,
    const int* __restrict__ cursor, const uint2* __restrict__ adj)
{
    int n = blockIdx.x * 4 + (threadIdx.x >> 6);   // 37500 blocks exact
    int lane = threadIdx.x & 63;
    int beg = (n == 0) ? 0 : cursor[n - 1];
    int end = cursor[n];

    float a = 0.f;
    int j = beg;
    for (; j + 3 < end; j += 4) {
        uint2 e0 = adj[j], e1 = adj[j + 1], e2 = adj[j + 2], e3 = adj[j + 3];
        float v0 = b2f(emb_in[(size_t)e0.x * DD + lane]);
        float v1 = b2f(emb_in[(size_t)e1.x * DD + lane]);
        float v2 = b2f(emb_in[(size_t)e2.x * DD + lane]);
        float v3 = b2f(emb_in[(size_t)e3.x * DD + lane]);
        a += __uint_as_float(e0.y) * v0;
        a += __uint_as_float(e1.y) * v1;
        a += __uint_as_float(e2.y) * v2;
        a += __uint_as_float(e3.y) * v3;
    }
    for (; j < end; ++j) {
        uint2 e0 = adj[j];
        a += __uint_as_float(e0.y) * b2f(emb_in[(size_t)e0.x * DD + lane]);
    }

    float s = a;
    #pragma unroll
    for (int off = 32; off; off >>= 1) s += __shfl_xor(s, off);
    float m = s * (1.f / 64.f);
    float dlt = a - m;
    float vv = dlt * dlt;
    #pragma unroll
    for (int off = 32; off; off >>= 1) vv += __shfl_xor(vv, off);
    float var = vv * (1.f / 64.f);
    float y = dlt * rsqrtf(var + LN_EPS);

    size_t o = (size_t)n * DD + lane;
    float e_new = y + b2f(emb_in[o]);
    emb_out[o] = f2b(e_new);
    if (n >= N_USERS)
        acc_items[(size_t)(n - N_USERS) * DD + lane] += e_new;
}

// ---------------------------------------------------------------------------
// K4: accumulate sampled rows directly into out
// ---------------------------------------------------------------------------
__global__ __launch_bounds__(256) void gather_acc_k(
    const int* __restrict__ users, const int* __restrict__ pos,
    const int* __restrict__ neg, const unsigned short* __restrict__ emb_state,
    float* __restrict__ out, int init)
{
    int gid = blockIdx.x * 256 + threadIdx.x;   // 3*BATCH*DD = 786432
    int part = gid / (BATCH * DD);
    int r = gid - part * (BATCH * DD);
    int b = r >> 6, c = r & 63;
    int node;
    if (part == 0)      node = users[b];
    else if (part == 1) node = N_USERS + pos[b];
    else                node = N_USERS + neg[b];
    float v = b2f(emb_state[(size_t)node * DD + c]);
    if (init) out[gid] = v;
    else      out[gid] += v;
}

// ---------------------------------------------------------------------------
// K5: content loss
// ---------------------------------------------------------------------------
__global__ __launch_bounds__(256) void loss_k(
    const float* __restrict__ acc_items, const float* __restrict__ ic,
    float* __restrict__ loss_slot)
{
    const int total = N_ITEMS * DD;
    int stride = gridDim.x * 256;
    float p = 0.f;
    for (int i = blockIdx.x * 256 + threadIdx.x; i < total; i += stride) {
        float d = acc_items[i] * 0.25f - ic[i];
        p += d * d;
    }
    #pragma unroll
    for (int off = 32; off; off >>= 1) p += __shfl_xor(p, off);
    __shared__ float red[4];
    if ((threadIdx.x & 63) == 0) red[threadIdx.x >> 6] = p;
    __syncthreads();
    if (threadIdx.x == 0)
        atomicAdd(loss_slot, red[0] + red[1] + red[2] + red[3]);
}

// ---------------------------------------------------------------------------
// K6: out *= 0.25 ; write loss element
// ---------------------------------------------------------------------------
__global__ __launch_bounds__(256) void final_out_k(
    const float* __restrict__ loss_slot, float* __restrict__ out)
{
    int gid = blockIdx.x * 256 + threadIdx.x;
    out[gid] *= 0.25f;
    if (gid == 0)
        out[3 * BATCH * DD] =
            loss_slot[0] * (CONTENT_LOSS_W / (float)(N_ITEMS * DD));
}

// ---------------------------------------------------------------------------
extern "C" void kernel_launch(void* const* d_in, const int* in_sizes, int n_in,
                              void* d_out, int out_size, void* d_ws, size_t ws_size,
                              hipStream_t stream)
{
    const int* users = (const int*)d_in[0];
    const int* pos   = (const int*)d_in[1];
    const int* neg   = (const int*)d_in[2];
    const int* es    = (const int*)d_in[3];
    const int* ed    = (const int*)d_in[4];
    const float* ew  = (const float*)d_in[5];
    const float* ue  = (const float*)d_in[6];
    const float* ie  = (const float*)d_in[7];
    const float* cf  = (const float*)d_in[8];
    const float* Wp  = (const float*)d_in[9];
    const float* bp  = (const float*)d_in[10];
    const float* wg  = (const float*)d_in[11];
    const float* bg  = (const float*)d_in[12];
    float* out = (float*)d_out;

    // ---- workspace layout (~103 MB) ----
    unsigned short* embA = (unsigned short*)d_ws;             // 19.2 MB
    unsigned short* embB = embA + (size_t)N_NODES * DD;       // 19.2 MB
    float* acc_items = (float*)(embB + (size_t)N_NODES * DD); // 12.8 MB
    float* ic        = acc_items + (size_t)N_ITEMS * DD;      // 12.8 MB
    float* loss_slot = ic + (size_t)N_ITEMS * DD;             // 64 B
    int*   cursor    = (int*)(loss_slot + 16);                // 600 KB
    int*   partials  = cursor + 150016;                       // 1 KB
    uint2* adj       = (uint2*)(partials + 256);              // 38.4 MB

    hipMemsetAsync(cursor, 0, 150016 * sizeof(int), stream);
    hipMemsetAsync(loss_slot, 0, sizeof(float), stream);

    init_users_k<<<(N_USERS * DD / 4) / 256, 256, 0, stream>>>(ue, embA);
    content_combine_k<<<N_ITEMS / 16, 256, 0, stream>>>(cf, Wp, bp, wg, bg, ie,
                                                        ic, embA, acc_items);
    gather_acc_k<<<3 * BATCH * DD / 256, 256, 0, stream>>>(users, pos, neg,
                                                           embA, out, 1);
    // CSR build
    hist_k<<<(N_EDGES_C / 4 + 255) / 256, 256, 0, stream>>>(ed, cursor);
    scan_blocksum_k<<<SCAN_NBLK, SCAN_BLK, 0, stream>>>(cursor, partials);
    scan_partials_k<<<1, 256, 0, stream>>>(partials);
    scan_write_k<<<SCAN_NBLK, SCAN_BLK, 0, stream>>>(partials, cursor);
    fill_k<<<N_EDGES_C / 256, 256, 0, stream>>>(ed, es, ew, cursor, adj);

    // 3 propagation layers, ping-pong
    unsigned short* cur = embA;
    unsigned short* nxt = embB;
    for (int l = 0; l < 3; ++l) {
        agg_ln_k<<<N_NODES / 4, 256, 0, stream>>>(cur, nxt, acc_items,
                                                  cursor, adj);
        gather_acc_k<<<3 * BATCH * DD / 256, 256, 0, stream>>>(users, pos, neg,
                                                               nxt, out, 0);
        unsigned short* t = cur; cur = nxt; nxt = t;
    }

    loss_k<<<2048, 256, 0, stream>>>(acc_items, ic, loss_slot);
    final_out_k<<<3 * BATCH * DD / 256, 256, 0, stream>>>(loss_slot, out);
}